// Round 1
// baseline (162.144 us; speedup 1.0000x reference)
//
#include <hip/hip_runtime.h>

// AdderNet CNN: conv1(L1) -> BN+ReLU -> pool4 -> conv2(L1) -> BN+ReLU -> pool2 -> FC(L1) -> BN
// Shapes: in [64,1,499,12]; conv1 out [64,5,488,8]; pool1 [64,5,122,2];
// conv2 out [64,10,118,2]; pool2 [64,10,59,1] -> flat [64,590]; fc [64,10].
//
// ws layout: [0,512) = 64 doubles of BN stats accumulators
//   stats[0..4]   sum  conv1-ch ; stats[8..12]  sumsq conv1-ch
//   stats[16..25] sum  conv2-ch ; stats[32..41] sumsq conv2-ch
// then floats: A (conv1 out, 1249280), B (pool1, 78080), C (conv2, 151040), D (pool2, 37760)

#define BN_EPS 1e-5f

__global__ void zero_stats_kernel(double* stats) {
    if (threadIdx.x < 64) stats[threadIdx.x] = 0.0;
}

// conv1: block = (b, co, ytile); 1280 blocks x 256 threads. Image band staged in LDS.
__global__ __launch_bounds__(256) void conv1_kernel(
    const float* __restrict__ in, const float* __restrict__ w1,
    float* __restrict__ A, double* __restrict__ stats)
{
    int bid = blockIdx.x;
    int t  = bid & 3;          // ytile: rows [t*122, t*122+122)
    int bc = bid >> 2;
    int co = bc % 5;
    int b  = bc / 5;

    __shared__ float wsm[60];
    if (threadIdx.x < 60) wsm[threadIdx.x] = w1[co * 60 + threadIdx.x];

    __shared__ float img[133 * 12];   // 122 out rows need 133 input rows
    const float* ip = in + b * (499 * 12) + t * 122 * 12;
    for (int i = threadIdx.x; i < 133 * 12; i += 256) img[i] = ip[i];
    __syncthreads();

    float ls = 0.f, lss = 0.f;
    float* Ap = A + ((size_t)(b * 5 + co) * 488 + t * 122) * 8;
    for (int idx = threadIdx.x; idx < 122 * 8; idx += 256) {
        int y = idx >> 3, x = idx & 7;
        float s = 0.f;
        #pragma unroll
        for (int kh = 0; kh < 12; kh++) {
            const float* r = &img[(y + kh) * 12 + x];
            const float* w = &wsm[kh * 5];
            #pragma unroll
            for (int kw = 0; kw < 5; kw++)
                s += fabsf(r[kw] - w[kw]);
        }
        float o = -s;
        Ap[idx] = o;
        ls += o; lss += o * o;
    }

    __shared__ double rs[256], rss[256];
    rs[threadIdx.x] = (double)ls; rss[threadIdx.x] = (double)lss;
    __syncthreads();
    for (int ofs = 128; ofs > 0; ofs >>= 1) {
        if (threadIdx.x < ofs) {
            rs[threadIdx.x]  += rs[threadIdx.x + ofs];
            rss[threadIdx.x] += rss[threadIdx.x + ofs];
        }
        __syncthreads();
    }
    if (threadIdx.x == 0) {
        atomicAdd(&stats[co],     rs[0]);
        atomicAdd(&stats[8 + co], rss[0]);
    }
}

// BN1 + ReLU + maxpool 4x4 : [64,5,488,8] -> [64,5,122,2]
__global__ __launch_bounds__(256) void pool1_kernel(
    const float* __restrict__ A, const double* __restrict__ stats,
    const float* __restrict__ g1, const float* __restrict__ b1,
    float* __restrict__ Bo)
{
    int e = blockIdx.x * 256 + threadIdx.x;
    if (e >= 64 * 5 * 122 * 2) return;
    int px = e & 1;
    int py = (e >> 1) % 122;
    int c  = (e / 244) % 5;
    int b  = e / 1220;

    double N = 64.0 * 488.0 * 8.0;
    double m = stats[c] / N;
    double v = stats[8 + c] / N - m * m;
    float scale = g1[c] * rsqrtf((float)v + BN_EPS);
    float shift = b1[c] - (float)m * scale;

    const float* Ap = A + ((size_t)(b * 5 + c) * 488 + py * 4) * 8 + px * 4;
    float mx = 0.f;  // ReLU floor
    #pragma unroll
    for (int dy = 0; dy < 4; dy++)
        #pragma unroll
        for (int dx = 0; dx < 4; dx++)
            mx = fmaxf(mx, Ap[dy * 8 + dx] * scale + shift);
    Bo[e] = mx;
}

// conv2: block = (b, co); 640 blocks x 256 threads (236 active). B[b] staged in LDS.
__global__ __launch_bounds__(256) void conv2_kernel(
    const float* __restrict__ Bi, const float* __restrict__ w2,
    float* __restrict__ C, double* __restrict__ stats)
{
    int bid = blockIdx.x;
    int co = bid % 10;
    int b  = bid / 10;
    int tid = threadIdx.x;

    __shared__ float wsm[25];
    if (tid < 25) wsm[tid] = w2[co * 25 + tid];
    __shared__ float img[5 * 122 * 2];
    for (int i = tid; i < 1220; i += 256) img[i] = Bi[b * 1220 + i];
    __syncthreads();

    float ls = 0.f, lss = 0.f;
    if (tid < 236) {
        int y = tid >> 1, x = tid & 1;
        float s = 0.f;
        #pragma unroll
        for (int cin = 0; cin < 5; cin++)
            #pragma unroll
            for (int kh = 0; kh < 5; kh++)
                s += fabsf(img[(cin * 122 + y + kh) * 2 + x] - wsm[cin * 5 + kh]);
        float o = -s;
        C[((size_t)(b * 10 + co) * 118 + y) * 2 + x] = o;
        ls = o; lss = o * o;
    }

    __shared__ double rs[256], rss[256];
    rs[tid] = (double)ls; rss[tid] = (double)lss;
    __syncthreads();
    for (int ofs = 128; ofs > 0; ofs >>= 1) {
        if (tid < ofs) { rs[tid] += rs[tid + ofs]; rss[tid] += rss[tid + ofs]; }
        __syncthreads();
    }
    if (tid == 0) {
        atomicAdd(&stats[16 + co], rs[0]);
        atomicAdd(&stats[32 + co], rss[0]);
    }
}

// BN2 + ReLU + maxpool 2x2 : [64,10,118,2] -> [64,10,59,1]
__global__ __launch_bounds__(256) void pool2_kernel(
    const float* __restrict__ C, const double* __restrict__ stats,
    const float* __restrict__ g2, const float* __restrict__ b2,
    float* __restrict__ D)
{
    int e = blockIdx.x * 256 + threadIdx.x;
    if (e >= 64 * 10 * 59) return;
    int py = e % 59;
    int c  = (e / 59) % 10;
    int b  = e / 590;

    double N = 64.0 * 118.0 * 2.0;
    double m = stats[16 + c] / N;
    double v = stats[32 + c] / N - m * m;
    float scale = g2[c] * rsqrtf((float)v + BN_EPS);
    float shift = b2[c] - (float)m * scale;

    const float* Cp = C + ((size_t)(b * 10 + c) * 118 + py * 2) * 2;
    float mx = 0.f;
    #pragma unroll
    for (int i = 0; i < 4; i++) mx = fmaxf(mx, Cp[i] * scale + shift);
    D[e] = mx;
}

// FC adder + BN3, single block of 640 threads (thread = (b, co)).
__global__ __launch_bounds__(640) void fc_bn_kernel(
    const float* __restrict__ D, const float* __restrict__ wfc,
    const float* __restrict__ g3, const float* __restrict__ b3,
    float* __restrict__ out)
{
    int tid = threadIdx.x;
    int b = tid / 10, co = tid % 10;
    const float* dp = D + b * 590;
    const float* wp = wfc + co * 590;
    float s = 0.f;
    for (int k = 0; k < 590; k++) s += fabsf(dp[k] - wp[k]);
    float o = -s;

    __shared__ float sh[640];
    sh[tid] = o;
    __syncthreads();

    __shared__ float scale_s[10], shift_s[10];
    if (tid < 10) {
        double sm = 0.0, ss = 0.0;
        for (int bb = 0; bb < 64; bb++) {
            double v = (double)sh[bb * 10 + tid];
            sm += v; ss += v * v;
        }
        double m = sm / 64.0;
        double v = ss / 64.0 - m * m;
        float sc = g3[tid] * rsqrtf((float)v + BN_EPS);
        scale_s[tid] = sc;
        shift_s[tid] = b3[tid] - (float)m * sc;
    }
    __syncthreads();
    out[tid] = o * scale_s[co] + shift_s[co];
}

extern "C" void kernel_launch(void* const* d_in, const int* in_sizes, int n_in,
                              void* d_out, int out_size, void* d_ws, size_t ws_size,
                              hipStream_t stream) {
    const float* in  = (const float*)d_in[0];
    const float* w1  = (const float*)d_in[1];
    const float* g1  = (const float*)d_in[2];
    const float* b1  = (const float*)d_in[3];
    const float* w2  = (const float*)d_in[4];
    const float* g2  = (const float*)d_in[5];
    const float* b2  = (const float*)d_in[6];
    const float* wfc = (const float*)d_in[7];
    const float* g3  = (const float*)d_in[8];
    const float* b3  = (const float*)d_in[9];
    float* out = (float*)d_out;

    double* stats = (double*)d_ws;
    float* A  = (float*)((char*)d_ws + 512);
    float* Bv = A  + 1249280;   // 64*5*488*8
    float* Cv = Bv + 78080;     // 64*5*122*2
    float* Dv = Cv + 151040;    // 64*10*118*2
    // Dv: 37760 floats; total ws use ~5.8 MB

    zero_stats_kernel<<<1, 64, 0, stream>>>(stats);
    conv1_kernel<<<1280, 256, 0, stream>>>(in, w1, A, stats);
    pool1_kernel<<<(78080 + 255) / 256, 256, 0, stream>>>(A, stats, g1, b1, Bv);
    conv2_kernel<<<640, 256, 0, stream>>>(Bv, w2, Cv, stats);
    pool2_kernel<<<(37760 + 255) / 256, 256, 0, stream>>>(Cv, stats, g2, b2, Dv);
    fc_bn_kernel<<<1, 640, 0, stream>>>(Dv, wfc, g3, b3, out);
}

// Round 3
// 114.837 us; speedup vs baseline: 1.4119x; 1.4119x over previous
//
#include <hip/hip_runtime.h>

// AdderNet CNN: conv1(L1) -> BN+ReLU -> pool4 -> conv2(L1) -> BN+ReLU -> pool2 -> FC(L1) -> BN
// Shapes: in [64,1,499,12]; conv1 out [64,5,488,8]; pool1 [64,5,122,2];
// conv2 out [64,10,118,2]; pool2 [64,10,59,1] -> flat [64,590]; fc [64,10].
//
// ws layout: [0,512) = 64 doubles of BN stats accumulators
//   stats[0..4]   sum  conv1-ch ; stats[8..12]  sumsq conv1-ch
//   stats[16..25] sum  conv2-ch ; stats[32..41] sumsq conv2-ch
// then floats: A (conv1 out), B (pool1), C (conv2), D (pool2), E (fc out 640)

#define BN_EPS 1e-5f

__global__ void zero_stats_kernel(double* stats) {
    if (threadIdx.x < 64) stats[threadIdx.x] = 0.0;
}

// conv1: block = (b, co, ytile); 1280 blocks x 128 threads.
// Thread = one output row (122 active). Per kh: one 12-float row via 3x ds_read_b128,
// slid across the 8 x-outputs in registers. Weights in per-thread regs (wave-uniform).
__global__ __launch_bounds__(128) void conv1_kernel(
    const float* __restrict__ in, const float* __restrict__ w1,
    float* __restrict__ A, double* __restrict__ stats)
{
    int bid = blockIdx.x;
    int t  = bid & 3;          // ytile: rows [t*122, t*122+122)
    int bc = bid >> 2;
    int co = bc % 5;
    int b  = bc / 5;
    int tid = threadIdx.x;

    __shared__ float img[133 * 12 + 4];   // 122 out rows need 133 input rows
    const float4* ip4 = (const float4*)(in + b * (499 * 12) + t * (122 * 12));
    float4* img4 = (float4*)img;
    for (int i = tid; i < 399; i += 128) img4[i] = ip4[i];   // 1596 floats

    float w[60];
    #pragma unroll
    for (int i = 0; i < 60; i++) w[i] = w1[co * 60 + i];
    __syncthreads();

    float ls = 0.f, lss = 0.f;
    if (tid < 122) {
        int y = tid;
        float s[8] = {0.f,0.f,0.f,0.f,0.f,0.f,0.f,0.f};
        #pragma unroll
        for (int kh = 0; kh < 12; kh++) {
            const float* rp = &img[(y + kh) * 12];
            float4 r0 = *(const float4*)(rp);
            float4 r1 = *(const float4*)(rp + 4);
            float4 r2 = *(const float4*)(rp + 8);
            float row[12] = {r0.x,r0.y,r0.z,r0.w, r1.x,r1.y,r1.z,r1.w, r2.x,r2.y,r2.z,r2.w};
            #pragma unroll
            for (int x = 0; x < 8; x++) {
                #pragma unroll
                for (int kw = 0; kw < 5; kw++)
                    s[x] += fabsf(row[x + kw] - w[kh * 5 + kw]);
            }
        }
        float4 o0, o1;
        o0.x = -s[0]; o0.y = -s[1]; o0.z = -s[2]; o0.w = -s[3];
        o1.x = -s[4]; o1.y = -s[5]; o1.z = -s[6]; o1.w = -s[7];
        float* Ap = A + ((size_t)(b * 5 + co) * 488 + t * 122 + y) * 8;
        *(float4*)(Ap)     = o0;
        *(float4*)(Ap + 4) = o1;
        #pragma unroll
        for (int x = 0; x < 8; x++) { float o = -s[x]; ls += o; lss += o * o; }
    }

    __shared__ double rs[128], rss[128];
    rs[tid] = (double)ls; rss[tid] = (double)lss;
    __syncthreads();
    for (int ofs = 64; ofs > 0; ofs >>= 1) {
        if (tid < ofs) { rs[tid] += rs[tid + ofs]; rss[tid] += rss[tid + ofs]; }
        __syncthreads();
    }
    if (tid == 0) {
        atomicAdd(&stats[co],     rs[0]);
        atomicAdd(&stats[8 + co], rss[0]);
    }
}

// BN1 + ReLU + maxpool 4x4 : [64,5,488,8] -> [64,5,122,2]
// Max over RAW conv values (all <= 0!) -> init -inf; affine+ReLU after (scale>0).
__global__ __launch_bounds__(256) void pool1_kernel(
    const float* __restrict__ A, const double* __restrict__ stats,
    const float* __restrict__ g1, const float* __restrict__ b1,
    float* __restrict__ Bo)
{
    int e = blockIdx.x * 256 + threadIdx.x;
    if (e >= 64 * 5 * 122 * 2) return;
    int px = e & 1;
    int py = (e >> 1) % 122;
    int c  = (e / 244) % 5;
    int b  = e / 1220;

    double N = 64.0 * 488.0 * 8.0;
    double m = stats[c] / N;
    double v = stats[8 + c] / N - m * m;
    float scale = g1[c] * rsqrtf((float)v + BN_EPS);
    float shift = b1[c] - (float)m * scale;

    const float* Ap = A + ((size_t)(b * 5 + c) * 488 + py * 4) * 8 + px * 4;
    float mx = -3.0e38f;                     // raw conv outputs are negative!
    #pragma unroll
    for (int dy = 0; dy < 4; dy++) {
        float4 r = *(const float4*)(Ap + dy * 8);
        mx = fmaxf(mx, fmaxf(fmaxf(r.x, r.y), fmaxf(r.z, r.w)));
    }
    float val = mx * scale + shift;
    Bo[e] = val > 0.f ? val : 0.f;
}

// conv2: block = (b, co); 640 blocks x 256 threads (236 active). B[b] staged in LDS.
__global__ __launch_bounds__(256) void conv2_kernel(
    const float* __restrict__ Bi, const float* __restrict__ w2,
    float* __restrict__ C, double* __restrict__ stats)
{
    int bid = blockIdx.x;
    int co = bid % 10;
    int b  = bid / 10;
    int tid = threadIdx.x;

    __shared__ float wsm[25];
    if (tid < 25) wsm[tid] = w2[co * 25 + tid];
    __shared__ float img[5 * 122 * 2];
    for (int i = tid; i < 1220; i += 256) img[i] = Bi[b * 1220 + i];
    __syncthreads();

    float ls = 0.f, lss = 0.f;
    if (tid < 236) {
        int y = tid >> 1, x = tid & 1;
        float s = 0.f;
        #pragma unroll
        for (int cin = 0; cin < 5; cin++)
            #pragma unroll
            for (int kh = 0; kh < 5; kh++)
                s += fabsf(img[(cin * 122 + y + kh) * 2 + x] - wsm[cin * 5 + kh]);
        float o = -s;
        C[((size_t)(b * 10 + co) * 118 + y) * 2 + x] = o;
        ls = o; lss = o * o;
    }

    __shared__ double rs[256], rss[256];
    rs[tid] = (double)ls; rss[tid] = (double)lss;
    __syncthreads();
    for (int ofs = 128; ofs > 0; ofs >>= 1) {
        if (tid < ofs) { rs[tid] += rs[tid + ofs]; rss[tid] += rss[tid + ofs]; }
        __syncthreads();
    }
    if (tid == 0) {
        atomicAdd(&stats[16 + co], rs[0]);
        atomicAdd(&stats[32 + co], rss[0]);
    }
}

// BN2 + ReLU + maxpool 2x2 : [64,10,118,2] -> [64,10,59,1]
__global__ __launch_bounds__(256) void pool2_kernel(
    const float* __restrict__ C, const double* __restrict__ stats,
    const float* __restrict__ g2, const float* __restrict__ b2,
    float* __restrict__ D)
{
    int e = blockIdx.x * 256 + threadIdx.x;
    if (e >= 64 * 10 * 59) return;
    int py = e % 59;
    int c  = (e / 59) % 10;
    int b  = e / 590;

    double N = 64.0 * 118.0 * 2.0;
    double m = stats[16 + c] / N;
    double v = stats[32 + c] / N - m * m;
    float scale = g2[c] * rsqrtf((float)v + BN_EPS);
    float shift = b2[c] - (float)m * scale;

    const float* Cp = C + ((size_t)(b * 10 + c) * 118 + py * 2) * 2;
    float4 r = *(const float4*)Cp;
    float mx = fmaxf(fmaxf(r.x, r.y), fmaxf(r.z, r.w));   // no floor: raw max
    float v2 = mx * scale + shift;
    D[e] = v2 > 0.f ? v2 : 0.f;
}

// FC adder: one wave per (b,co) pair; 640 waves = 160 blocks x 256 threads.
__global__ __launch_bounds__(256) void fc_kernel(
    const float* __restrict__ D, const float* __restrict__ wfc,
    float* __restrict__ E)
{
    int pair = blockIdx.x * 4 + (threadIdx.x >> 6);
    int lane = threadIdx.x & 63;
    int b = pair / 10, co = pair % 10;
    const float* dp = D + b * 590;
    const float* wp = wfc + co * 590;
    float s = 0.f;
    #pragma unroll
    for (int j = 0; j < 10; j++) {
        int k = lane + j * 64;
        if (k < 590) s += fabsf(dp[k] - wp[k]);
    }
    #pragma unroll
    for (int ofs = 32; ofs > 0; ofs >>= 1) s += __shfl_down(s, ofs, 64);
    if (lane == 0) E[pair] = -s;
}

// BN3 over E [64,10] -> out [64,10]
__global__ __launch_bounds__(640) void bn3_kernel(
    const float* __restrict__ E,
    const float* __restrict__ g3, const float* __restrict__ b3,
    float* __restrict__ out)
{
    int tid = threadIdx.x;
    int co = tid % 10;
    float o = E[tid];
    __shared__ float scale_s[10], shift_s[10];
    if (tid < 10) {
        double sm = 0.0, ss = 0.0;
        for (int bb = 0; bb < 64; bb++) {
            double v = (double)E[bb * 10 + tid];
            sm += v; ss += v * v;
        }
        double m = sm / 64.0;
        double v = ss / 64.0 - m * m;
        float sc = g3[tid] * rsqrtf((float)v + BN_EPS);
        scale_s[tid] = sc;
        shift_s[tid] = b3[tid] - (float)m * sc;
    }
    __syncthreads();
    out[tid] = o * scale_s[co] + shift_s[co];
}

extern "C" void kernel_launch(void* const* d_in, const int* in_sizes, int n_in,
                              void* d_out, int out_size, void* d_ws, size_t ws_size,
                              hipStream_t stream) {
    const float* in  = (const float*)d_in[0];
    const float* w1  = (const float*)d_in[1];
    const float* g1  = (const float*)d_in[2];
    const float* b1  = (const float*)d_in[3];
    const float* w2  = (const float*)d_in[4];
    const float* g2  = (const float*)d_in[5];
    const float* b2  = (const float*)d_in[6];
    const float* wfc = (const float*)d_in[7];
    const float* g3  = (const float*)d_in[8];
    const float* b3  = (const float*)d_in[9];
    float* out = (float*)d_out;

    double* stats = (double*)d_ws;
    float* A  = (float*)((char*)d_ws + 512);
    float* Bv = A  + 1249280;   // 64*5*488*8
    float* Cv = Bv + 78080;     // 64*5*122*2
    float* Dv = Cv + 151040;    // 64*10*118*2
    float* Ev = Dv + 37760;     // 640
    // total ws use ~5.8 MB

    zero_stats_kernel<<<1, 64, 0, stream>>>(stats);
    conv1_kernel<<<1280, 128, 0, stream>>>(in, w1, A, stats);
    pool1_kernel<<<(78080 + 255) / 256, 256, 0, stream>>>(A, stats, g1, b1, Bv);
    conv2_kernel<<<640, 256, 0, stream>>>(Bv, w2, Cv, stats);
    pool2_kernel<<<(37760 + 255) / 256, 256, 0, stream>>>(Cv, stats, g2, b2, Dv);
    fc_kernel<<<160, 256, 0, stream>>>(Dv, wfc, Ev);
    bn3_kernel<<<1, 640, 0, stream>>>(Ev, g3, b3, out);
}

// Round 5
// 106.364 us; speedup vs baseline: 1.5244x; 1.0797x over previous
//
#include <hip/hip_runtime.h>

// AdderNet CNN, fused: conv1+pool4 -> conv2+pool2 -> FC -> BN3.
// BN affines are folded into consumers (max-pool over raw conv commutes with the
// positive-scale BN affine; stats are computed over RAW conv outputs as required).
// Shapes: in [64,1,499,12]; pooled1 raw [64,5,122,2]; pooled2 raw [64,10,59];
// fc out E [64,10]; final [64,10].
//
// ws layout: [0,512) = 64 doubles of BN stats accumulators
//   stats[0..4]   sum  conv1-ch ; stats[8..12]  sumsq conv1-ch (over 64*488*8 raw vals)
//   stats[16..25] sum  conv2-ch ; stats[32..41] sumsq conv2-ch (over 64*118*2 raw vals)
// floats after: Bv raw-pooled1 (78080), Draw raw-pooled2 (37760), E (640)

#define BN_EPS 1e-5f

__global__ void zero_stats_kernel(double* stats) {
    if (threadIdx.x < 64) stats[threadIdx.x] = 0.0;
}

// conv1 + maxpool4x4 (on raw values) + BN1 stats.
// grid 640 = (b*5+co)*2 + t ; block 256. Tile t covers out rows [t*244, t*244+244).
// Thread = one out-row (244 active): 8 cols x 60 weights = 480 L1 terms in regs.
// Pool: col-max in regs, row-max via 4-lane shfl (windows are wave-aligned: 4|64).
__global__ __launch_bounds__(256) void conv1p1_kernel(
    const float* __restrict__ in, const float* __restrict__ w1,
    float* __restrict__ Bo, double* __restrict__ stats)
{
    int bid = blockIdx.x;
    int t  = bid & 1;
    int bc = bid >> 1;
    int co = bc % 5;
    int b  = bc / 5;
    int tid = threadIdx.x;

    // stage input rows [t*244, t*244+255) : 255 rows x 12 = 3060 floats
    __shared__ float img[255 * 12 + 4];
    const float4* ip4 = (const float4*)(in + b * 5988 + t * 2928);
    float4* img4 = (float4*)img;
    for (int i = tid; i < 765; i += 256) img4[i] = ip4[i];

    float w[60];
    #pragma unroll
    for (int i = 0; i < 60; i++) w[i] = w1[co * 60 + i];
    __syncthreads();

    float ls = 0.f, lss = 0.f;
    float m0 = 0.f, m1 = 0.f;
    if (tid < 244) {
        int y = tid;
        float s[8] = {0.f,0.f,0.f,0.f,0.f,0.f,0.f,0.f};
        #pragma unroll
        for (int kh = 0; kh < 12; kh++) {
            const float* rp = &img[(y + kh) * 12];
            float4 r0 = *(const float4*)(rp);
            float4 r1 = *(const float4*)(rp + 4);
            float4 r2 = *(const float4*)(rp + 8);
            float row[12] = {r0.x,r0.y,r0.z,r0.w, r1.x,r1.y,r1.z,r1.w, r2.x,r2.y,r2.z,r2.w};
            #pragma unroll
            for (int x = 0; x < 8; x++) {
                #pragma unroll
                for (int kw = 0; kw < 5; kw++)
                    s[x] += fabsf(row[x + kw] - w[kh * 5 + kw]);
            }
        }
        float o[8];
        #pragma unroll
        for (int x = 0; x < 8; x++) { o[x] = -s[x]; ls += o[x]; lss += o[x] * o[x]; }
        m0 = fmaxf(fmaxf(o[0], o[1]), fmaxf(o[2], o[3]));
        m1 = fmaxf(fmaxf(o[4], o[5]), fmaxf(o[6], o[7]));
    }
    // 4-row pool reduction within the wave (window lanes 4q..4q+3, all active)
    m0 = fmaxf(m0, __shfl_down(m0, 1, 64));
    m0 = fmaxf(m0, __shfl_down(m0, 2, 64));
    m1 = fmaxf(m1, __shfl_down(m1, 1, 64));
    m1 = fmaxf(m1, __shfl_down(m1, 2, 64));
    if (tid < 244 && (tid & 3) == 0) {
        int p = t * 61 + (tid >> 2);
        float* bp = Bo + ((size_t)(b * 5 + co) * 122 + p) * 2;
        bp[0] = m0; bp[1] = m1;
    }

    __shared__ double rs[256], rss[256];
    rs[tid] = (double)ls; rss[tid] = (double)lss;
    __syncthreads();
    for (int ofs = 128; ofs > 0; ofs >>= 1) {
        if (tid < ofs) { rs[tid] += rs[tid + ofs]; rss[tid] += rss[tid + ofs]; }
        __syncthreads();
    }
    if (tid == 0) {
        atomicAdd(&stats[co],     rs[0]);
        atomicAdd(&stats[8 + co], rss[0]);
    }
}

// conv2 + maxpool2x2 (raw) + BN2 stats. BN1 affine+ReLU applied during stage-in.
// grid 640 = b*10+co ; block 64 (1 wave). Thread = pooled row py (59 active),
// computes its 2x2 raw conv2 window (4 x 25 L1 terms).
// NOTE: stats is non-const — read BN1 stats (written by conv1p1, same-stream order
// guarantees visibility) AND atomically accumulate BN2 stats.
__global__ __launch_bounds__(64) void conv2p2_kernel(
    const float* __restrict__ Bi, double* __restrict__ stats,
    const float* __restrict__ g1, const float* __restrict__ b1,
    const float* __restrict__ w2,
    float* __restrict__ Draw)
{
    int bid = blockIdx.x;
    int co = bid % 10;
    int b  = bid / 10;
    int tid = threadIdx.x;

    // BN1 scale/shift per input channel (uniform across lanes)
    float sc1[5], sh1[5];
    const double N1 = 64.0 * 488.0 * 8.0;
    #pragma unroll
    for (int c = 0; c < 5; c++) {
        double m = stats[c] / N1;
        double v = stats[8 + c] / N1 - m * m;
        sc1[c] = g1[c] * rsqrtf((float)v + BN_EPS);
        sh1[c] = b1[c] - (float)m * sc1[c];
    }

    __shared__ float img[5 * 122 * 2];   // post BN1+ReLU
    const float4* bp4 = (const float4*)(Bi + (size_t)b * 1220);
    float4* img4 = (float4*)img;
    for (int i = tid; i < 305; i += 64) {
        int c = i / 61;                  // 61 float4 per channel (244 floats)
        float4 r = bp4[i];
        r.x = fmaxf(0.f, r.x * sc1[c] + sh1[c]);
        r.y = fmaxf(0.f, r.y * sc1[c] + sh1[c]);
        r.z = fmaxf(0.f, r.z * sc1[c] + sh1[c]);
        r.w = fmaxf(0.f, r.w * sc1[c] + sh1[c]);
        img4[i] = r;
    }

    float w[25];
    #pragma unroll
    for (int i = 0; i < 25; i++) w[i] = w2[co * 25 + i];
    __syncthreads();

    float ls = 0.f, lss = 0.f;
    if (tid < 59) {
        const float2* img2 = (const float2*)img;
        float o[4];
        #pragma unroll
        for (int r = 0; r < 2; r++) {
            int row = 2 * tid + r;
            float s0 = 0.f, s1 = 0.f;
            #pragma unroll
            for (int cin = 0; cin < 5; cin++)
                #pragma unroll
                for (int kh = 0; kh < 5; kh++) {
                    float2 f = img2[cin * 122 + row + kh];
                    float wv = w[cin * 5 + kh];
                    s0 += fabsf(f.x - wv);
                    s1 += fabsf(f.y - wv);
                }
            o[r * 2]     = -s0;
            o[r * 2 + 1] = -s1;
        }
        #pragma unroll
        for (int i = 0; i < 4; i++) { ls += o[i]; lss += o[i] * o[i]; }
        Draw[(size_t)(b * 10 + co) * 59 + tid] =
            fmaxf(fmaxf(o[0], o[1]), fmaxf(o[2], o[3]));
    }

    // wave reduce + 1 atomic pair
    #pragma unroll
    for (int ofs = 32; ofs > 0; ofs >>= 1) {
        ls  += __shfl_down(ls, ofs, 64);
        lss += __shfl_down(lss, ofs, 64);
    }
    if (tid == 0) {
        atomicAdd(&stats[16 + co], (double)ls);
        atomicAdd(&stats[32 + co], (double)lss);
    }
}

// FC adder (BN2 affine+ReLU applied on load): one wave per (b,co); 160 blocks.
__global__ __launch_bounds__(256) void fc_kernel(
    const float* __restrict__ Draw, const double* __restrict__ stats,
    const float* __restrict__ g2, const float* __restrict__ b2,
    const float* __restrict__ wfc, float* __restrict__ E)
{
    int tid = threadIdx.x;
    __shared__ float sc2[10], sh2[10];
    if (tid < 10) {
        const double N2 = 64.0 * 118.0 * 2.0;
        double m = stats[16 + tid] / N2;
        double v = stats[32 + tid] / N2 - m * m;
        float sc = g2[tid] * rsqrtf((float)v + BN_EPS);
        sc2[tid] = sc;
        sh2[tid] = b2[tid] - (float)m * sc;
    }
    __syncthreads();

    int pair = blockIdx.x * 4 + (tid >> 6);
    int lane = tid & 63;
    int b = pair / 10, co = pair % 10;
    const float* dp = Draw + (size_t)b * 590;
    const float* wp = wfc + (size_t)co * 590;
    float s = 0.f;
    #pragma unroll
    for (int j = 0; j < 10; j++) {
        int k = lane + j * 64;
        if (k < 590) {
            int c = k / 59;
            float x = fmaxf(0.f, dp[k] * sc2[c] + sh2[c]);
            s += fabsf(x - wp[k]);
        }
    }
    #pragma unroll
    for (int ofs = 32; ofs > 0; ofs >>= 1) s += __shfl_down(s, ofs, 64);
    if (lane == 0) E[pair] = -s;
}

// BN3 over E [64,10] -> out [64,10]
__global__ __launch_bounds__(640) void bn3_kernel(
    const float* __restrict__ E,
    const float* __restrict__ g3, const float* __restrict__ b3,
    float* __restrict__ out)
{
    int tid = threadIdx.x;
    int co = tid % 10;
    float o = E[tid];
    __shared__ float scale_s[10], shift_s[10];
    if (tid < 10) {
        double sm = 0.0, ss = 0.0;
        for (int bb = 0; bb < 64; bb++) {
            double v = (double)E[bb * 10 + tid];
            sm += v; ss += v * v;
        }
        double m = sm / 64.0;
        double v = ss / 64.0 - m * m;
        float sc = g3[tid] * rsqrtf((float)v + BN_EPS);
        scale_s[tid] = sc;
        shift_s[tid] = b3[tid] - (float)m * sc;
    }
    __syncthreads();
    out[tid] = o * scale_s[co] + shift_s[co];
}

extern "C" void kernel_launch(void* const* d_in, const int* in_sizes, int n_in,
                              void* d_out, int out_size, void* d_ws, size_t ws_size,
                              hipStream_t stream) {
    const float* in  = (const float*)d_in[0];
    const float* w1  = (const float*)d_in[1];
    const float* g1  = (const float*)d_in[2];
    const float* b1  = (const float*)d_in[3];
    const float* w2  = (const float*)d_in[4];
    const float* g2  = (const float*)d_in[5];
    const float* b2  = (const float*)d_in[6];
    const float* wfc = (const float*)d_in[7];
    const float* g3  = (const float*)d_in[8];
    const float* b3  = (const float*)d_in[9];
    float* out = (float*)d_out;

    double* stats = (double*)d_ws;
    float* Bv   = (float*)((char*)d_ws + 512);  // raw pooled1 [64,5,122,2] = 78080
    float* Draw = Bv + 78080;                   // raw pooled2 [64,10,59]   = 37760
    float* Ev   = Draw + 37760;                 // fc out 640

    zero_stats_kernel<<<1, 64, 0, stream>>>(stats);
    conv1p1_kernel<<<640, 256, 0, stream>>>(in, w1, Bv, stats);
    conv2p2_kernel<<<640, 64, 0, stream>>>(Bv, stats, g1, b1, w2, Draw);
    fc_kernel<<<160, 256, 0, stream>>>(Draw, stats, g2, b2, wfc, Ev);
    bn3_kernel<<<1, 640, 0, stream>>>(Ev, g3, b3, out);
}